// Round 1
// baseline (1827.687 us; speedup 1.0000x reference)
//
#include <hip/hip_runtime.h>
#include <cstdint>
#include <cstddef>

typedef __attribute__((ext_vector_type(8))) short short8;
typedef __attribute__((ext_vector_type(4))) float f32x4;

#define MFMA16(a, b, c) __builtin_amdgcn_mfma_f32_16x16x32_bf16((a), (b), (c), 0, 0, 0)

constexpr int kB = 512, kS = 256, kI = 12, kH = 256, kA = 9;
constexpr int kNS = 8;    // hidden slices per btile (32 h-units each)
constexpr int kNB = 32;   // btiles (16 rows each)
constexpr int kNP = 16;   // btile PAIRS: block owns btiles (pair, pair+16)
constexpr int kT  = 512;  // 8 waves
constexpr int LDH = 264;  // padded LDS stride (bf16) for K=256 operand tiles
constexpr int LDG = 132;  // padded LDS stride (fp32) for 16x128 gate tiles
constexpr int kBH = kB * kH;
constexpr int FLS = 512;  // flag array stride per btile (ints)

// d_out layout (floats): [logits 512*9][h0 512*256][h1 512*256][c0 512*256][c1 512*256]
constexpr int OUT_H = kB * kA;              // 4608
constexpr int OUT_C = OUT_H + 2 * kBH;      // 266752

__device__ __forceinline__ short f2bf(float f) {  // RTNE fp32 -> bf16 bits
  uint32_t u = __float_as_uint(f);
  u += 0x7fffu + ((u >> 16) & 1u);
  return (short)(u >> 16);
}
__device__ __forceinline__ float fast_sigmoid(float v) {
  return __builtin_amdgcn_rcpf(1.f + __expf(-v));
}
__device__ __forceinline__ float fast_tanh(float v) {
  return 2.f * __builtin_amdgcn_rcpf(1.f + __expf(-2.f * v)) - 1.f;
}

// R5: btile-pairing. Each block time-multiplexes TWO independent btiles
// (X = pair, Y = pair+16) through the SAME weight registers and shared
// hA/hB/gate LDS. While btile X's exchange (store-drain -> flag RMW ->
// spin -> gather) propagates through the XCD L2, the block computes btile
// Y's head+elem, and vice versa. R4 exposed ~5K cy/phase of exchange
// stall (MfmaUtil 13%, VALU 21%, rest idle); pairing hides it.
// Grid = 128 blocks (1/CU); bid%8 == pair%8 so all 8 slices of both
// btiles of a pair stay on one XCD.

#define EMB_TILE(EMBA, B0, T)                                               \
  {                                                                         \
    const float* xr = x + ((size_t)((B0) + n16) * kS + (T)) * kI;           \
    short8 xa;                                                              \
    _Pragma("unroll")                                                       \
    for (int j = 0; j < 8; ++j) {                                           \
      const int k = quad * 8 + j;                                           \
      xa[j] = (k < kI) ? f2bf(xr[k]) : (short)0;                            \
    }                                                                       \
    _Pragma("unroll")                                                       \
    for (int i = 0; i < 2; ++i) {                                           \
      f32x4 z = {0.f, 0.f, 0.f, 0.f};                                       \
      f32x4 e = MFMA16(xa, wE[i], z);                                       \
      const int col = wave * 32 + i * 16 + n16;                             \
      _Pragma("unroll")                                                     \
      for (int r = 0; r < 4; ++r) {                                         \
        float v = e[r] + bembv[i];                                          \
        v = v > 0.f ? v : 0.f;                                              \
        EMBA[(quad * 4 + r) * LDH + col] = f2bf(v);                         \
      }                                                                     \
    }                                                                       \
  }

#define HEAD_TILE(EMBA)                                                     \
  {                                                                         \
    f32x4 a0 = {0.f, 0.f, 0.f, 0.f}, g1 = a0;                               \
    _Pragma("unroll")                                                       \
    for (int kk = 0; kk < 8; ++kk) {                                        \
      const short8 ha = *(const short8*)&hA[n16 * LDH + kk * 32 + quad * 8];\
      a0 = MFMA16(ha, wB[1][kk], a0);                                       \
      g1 = MFMA16(ha, wB[2][kk], g1);                                       \
    }                                                                       \
    _Pragma("unroll")                                                       \
    for (int kk = 0; kk < 8; ++kk) {                                        \
      const short8 e = *(const short8*)&EMBA[n16 * LDH + kk * 32 + quad*8]; \
      a0 = MFMA16(e, wB[0][kk], a0);                                        \
    }                                                                       \
    _Pragma("unroll")                                                       \
    for (int kk = 0; kk < 8; ++kk) {                                        \
      const short8 hb = *(const short8*)&hB[n16 * LDH + kk * 32 + quad*8];  \
      g1 = MFMA16(hb, wB[3][kk], g1);                                       \
    }                                                                       \
    const int lcol = (wave >> 1) * 32 + (wave & 1) * 16 + n16;              \
    _Pragma("unroll")                                                       \
    for (int r = 0; r < 4; ++r) {                                           \
      gL0[(quad * 4 + r) * LDG + lcol] = a0[r];                             \
      gL1[(quad * 4 + r) * LDG + lcol] = g1[r];                             \
    }                                                                       \
  }

#define ELEM_L0(B0, C0V)                                                    \
  if (p < kS) {                                                             \
    const float iv = gL0[erow * LDG +       ec] + bi0[0];                   \
    const float fv = gL0[erow * LDG +  32 + ec] + bi0[1];                   \
    const float gv = gL0[erow * LDG +  64 + ec] + bi0[2];                   \
    const float ov = gL0[erow * LDG +  96 + ec] + bi0[3];                   \
    const float c = fast_sigmoid(fv) * (C0V) + fast_sigmoid(iv) * fast_tanh(gv); \
    (C0V) = c;                                                              \
    const float h = fast_sigmoid(ov) * fast_tanh(c);                        \
    unsigned short* dst =                                                   \
        &h0ex[(size_t)par * kBH + (size_t)((B0) + erow) * kH + ecol];       \
    __hip_atomic_store(dst, (unsigned short)f2bf(h), __ATOMIC_RELAXED,      \
                       __HIP_MEMORY_SCOPE_AGENT);                           \
    if (p == kS - 1) {                                                      \
      dout[OUT_H + (size_t)((B0) + erow) * kH + ecol] = h;                  \
      dout[OUT_C + (size_t)((B0) + erow) * kH + ecol] = c;                  \
    }                                                                       \
  }

#define ELEM_L1(B0, C1V)                                                    \
  if (p >= 1) {                                                             \
    const float iv = gL1[erow * LDG +       ec] + bi1[0];                   \
    const float fv = gL1[erow * LDG +  32 + ec] + bi1[1];                   \
    const float gv = gL1[erow * LDG +  64 + ec] + bi1[2];                   \
    const float ov = gL1[erow * LDG +  96 + ec] + bi1[3];                   \
    const float c = fast_sigmoid(fv) * (C1V) + fast_sigmoid(iv) * fast_tanh(gv); \
    (C1V) = c;                                                              \
    const float h = fast_sigmoid(ov) * fast_tanh(c);                        \
    unsigned short* dst =                                                   \
        &h1ex[(size_t)par * kBH + (size_t)((B0) + erow) * kH + ecol];       \
    __hip_atomic_store(dst, (unsigned short)f2bf(h), __ATOMIC_RELAXED,      \
                       __HIP_MEMORY_SCOPE_AGENT);                           \
    if (p == kS) {                                                          \
      dout[OUT_H + kBH + (size_t)((B0) + erow) * kH + ecol] = h;            \
      dout[OUT_C + kBH + (size_t)((B0) + erow) * kH + ecol] = c;            \
    }                                                                       \
  }

#define GATHER_TILE(B0)                                                     \
  {                                                                         \
    const int rr = tid >> 5;                                                \
    const int cc = (tid & 31) * 8;                                          \
    const size_t base = (size_t)parg * kBH + (size_t)((B0) + rr) * kH + cc; \
    const uint64_t* s0 = (const uint64_t*)&h0ex[base];                      \
    const uint64_t* s1 = (const uint64_t*)&h1ex[base];                      \
    uint64_t va0 = __hip_atomic_load(s0 + 0, __ATOMIC_RELAXED, __HIP_MEMORY_SCOPE_AGENT); \
    uint64_t va1 = __hip_atomic_load(s0 + 1, __ATOMIC_RELAXED, __HIP_MEMORY_SCOPE_AGENT); \
    uint64_t vb0 = __hip_atomic_load(s1 + 0, __ATOMIC_RELAXED, __HIP_MEMORY_SCOPE_AGENT); \
    uint64_t vb1 = __hip_atomic_load(s1 + 1, __ATOMIC_RELAXED, __HIP_MEMORY_SCOPE_AGENT); \
    uint64_t* dA = (uint64_t*)&hA[rr * LDH + cc];                           \
    uint64_t* dB = (uint64_t*)&hB[rr * LDH + cc];                           \
    dA[0] = va0; dA[1] = va1;                                               \
    dB[0] = vb0; dB[1] = vb1;                                               \
  }

#define SPIN_WAIT(FL)                                                       \
  while (__hip_atomic_load((FL) + (p - 1), __ATOMIC_RELAXED,                \
                           __HIP_MEMORY_SCOPE_AGENT) < kNS)                 \
    __builtin_amdgcn_s_sleep(1);

__global__ __launch_bounds__(kT, 2) void lstm_scan_kernel(
    const float* __restrict__ x,
    const float* __restrict__ W_emb, const float* __restrict__ b_emb,
    const float* __restrict__ w_ih0, const float* __restrict__ w_hh0,
    const float* __restrict__ b_ih0, const float* __restrict__ b_hh0,
    const float* __restrict__ w_ih1, const float* __restrict__ w_hh1,
    const float* __restrict__ b_ih1, const float* __restrict__ b_hh1,
    unsigned short* __restrict__ h0ex, unsigned short* __restrict__ h1ex,
    int* __restrict__ flags,
    float* __restrict__ dout)
{
  const int tid   = threadIdx.x;
  const int pair  = blockIdx.x & (kNP - 1);  // bid%8 == pair%8 -> shared XCD
  const int slice = blockIdx.x >> 4;
  const int b0X   = pair * 16;
  const int b0Y   = (pair + 16) * 16;
  const int lane  = tid & 63;
  const int wave  = tid >> 6;
  const int n16   = lane & 15;
  const int quad  = lane >> 4;

  // Time-shared LDS: hA/hB and gate tiles serve X then Y within a superphase.
  __shared__ short embX[16 * LDH];   // emb(p) for btile X
  __shared__ short embY[16 * LDH];   // emb(p) for btile Y
  __shared__ short hA[16 * LDH];     // h0(p-1) of current btile
  __shared__ short hB[16 * LDH];     // h1(p-2) of current btile
  __shared__ float gL0[16 * LDG];    // layer0 gates 16 x 128 fp32
  __shared__ float gL1[16 * LDG];    // layer1 gates 16 x 128 fp32

  for (int i = tid; i < 16 * LDH; i += kT) { hA[i] = 0; hB[i] = 0; }

  // Weight B-fragments: wave owns gate cols [(wave>>1)*256 + slice*32 +
  // (wave&1)*16 + n16] — SHARED between btiles X and Y (same slice).
  const float* Wm[4] = { w_ih0, w_hh0, w_ih1, w_hh1 };
  short8 wB[4][8];
  {
    const int gcol = (wave >> 1) * kH + slice * 32 + (wave & 1) * 16 + n16;
#pragma unroll
    for (int mat = 0; mat < 4; ++mat) {
      const float* wp = Wm[mat] + (size_t)gcol * kH;
#pragma unroll
      for (int kk = 0; kk < 8; ++kk) {
        const float* p = wp + kk * 32 + quad * 8;
        const float4 f0 = *(const float4*)p;
        const float4 f1 = *(const float4*)(p + 4);
        short8 v;
        v[0] = f2bf(f0.x); v[1] = f2bf(f0.y); v[2] = f2bf(f0.z); v[3] = f2bf(f0.w);
        v[4] = f2bf(f1.x); v[5] = f2bf(f1.y); v[6] = f2bf(f1.z); v[7] = f2bf(f1.w);
        wB[mat][kk] = v;
      }
    }
  }
  // Embedding weights (K=12 zero-padded to 32); wave computes cols [wave*32,+32).
  short8 wE[2];
  float bembv[2];
#pragma unroll
  for (int i = 0; i < 2; ++i) {
    const int col = wave * 32 + i * 16 + n16;
    short8 v;
#pragma unroll
    for (int j = 0; j < 8; ++j) {
      const int k = quad * 8 + j;
      v[j] = (k < kI) ? f2bf(W_emb[col * kI + k]) : (short)0;
    }
    wE[i] = v;
    bembv[i] = b_emb[col];
  }
  // Elementwise mapping: thread = (row=tid>>5, col=tid&31); same cols both btiles.
  const int erow = tid >> 5;
  const int ec   = tid & 31;
  const int ecol = slice * 32 + ec;
  float bi0[4], bi1[4];
#pragma unroll
  for (int g = 0; g < 4; ++g) {
    bi0[g] = b_ih0[g * kH + ecol] + b_hh0[g * kH + ecol];
    bi1[g] = b_ih1[g * kH + ecol] + b_hh1[g * kH + ecol];
  }
  float c0X = 0.f, c1X = 0.f, c0Y = 0.f, c1Y = 0.f;

  // -------- prologue: emb(0) for both btiles --------
  EMB_TILE(embX, b0X, 0);
  EMB_TILE(embY, b0Y, 0);
  __syncthreads();

  int* const flX = flags + pair * FLS;
  int* const flY = flags + (pair + 16) * FLS;

  for (int p = 0; p <= kS; ++p) {
    const int par  = p & 1;
    const int parg = par ^ 1;  // (p-1)&1

    // ================= btile X =================
    // Exchange window for X(p-1) was the whole Y-section + emb of the
    // previous superphase (~2K+ cy) -> spin expected to hit first poll.
    if (p >= 1) { SPIN_WAIT(flX); GATHER_TILE(b0X); }
    __syncthreads();                    // gather visible -> head may read
    HEAD_TILE(embX);
    __syncthreads();                    // gate tiles ready
    ELEM_L0(b0X, c0X);
    ELEM_L1(b0X, c1X);
    __syncthreads();                    // drains vmcnt(0) -> stores IC-visible
    if (p < kS && tid == 0)
      __hip_atomic_fetch_add(flX + p, 1, __ATOMIC_RELAXED, __HIP_MEMORY_SCOPE_AGENT);

    // ================= btile Y =================
    if (p >= 1) { SPIN_WAIT(flY); GATHER_TILE(b0Y); }
    __syncthreads();
    HEAD_TILE(embY);
    __syncthreads();
    ELEM_L0(b0Y, c0Y);
    ELEM_L1(b0Y, c1Y);
    __syncthreads();
    if (p < kS && tid == 0)
      __hip_atomic_fetch_add(flY + p, 1, __ATOMIC_RELAXED, __HIP_MEMORY_SCOPE_AGENT);

    // ---- emb(p+1) both btiles: fills Y's publish->spin window ----
    if (p + 1 < kS) {
      EMB_TILE(embX, b0X, p + 1);
      EMB_TILE(embY, b0Y, p + 1);
    }
    // next superphase's pre-head barrier covers embX/embY visibility
  }
}

// LayerNorm + MLP head, exact fp32. One wave per batch row.
__global__ __launch_bounds__(64) void head_kernel(
    const float* __restrict__ h1last, const float* __restrict__ mask,
    const float* __restrict__ ln_g, const float* __restrict__ ln_b,
    const float* __restrict__ w1, const float* __restrict__ b1,
    const float* __restrict__ w2, const float* __restrict__ b2,
    float* __restrict__ out)
{
  const int r = blockIdx.x;
  const int lane = threadIdx.x;
  __shared__ float ns[kH];
  __shared__ float hd[32];
  const float4 v = *(const float4*)&h1last[r * kH + lane * 4];
  float vv[4] = {v.x, v.y, v.z, v.w};
  float s = vv[0] + vv[1] + vv[2] + vv[3];
#pragma unroll
  for (int off = 32; off > 0; off >>= 1) s += __shfl_xor(s, off, 64);
  const float mean = s * (1.f / kH);
  float q = 0.f;
#pragma unroll
  for (int j = 0; j < 4; ++j) { const float d = vv[j] - mean; q += d * d; }
#pragma unroll
  for (int off = 32; off > 0; off >>= 1) q += __shfl_xor(q, off, 64);
  const float rstd = rsqrtf(q * (1.f / kH) + 1e-5f);
#pragma unroll
  for (int j = 0; j < 4; ++j) {
    const int c = lane * 4 + j;
    ns[c] = (vv[j] - mean) * rstd * ln_g[c] + ln_b[c];
  }
  __syncthreads();
  if (lane < 32) {
    float a = b1[lane];
    const float* wr = w1 + lane * kH;
    for (int k = 0; k < kH; ++k) a += ns[k] * wr[k];
    hd[lane] = a > 0.f ? a : 0.f;
  }
  __syncthreads();
  if (lane < kA) {
    float a = b2[lane];
    const float* wr = w2 + lane * 32;
#pragma unroll
    for (int k = 0; k < 32; ++k) a += hd[k] * wr[k];
    a += (1.f - mask[r * kA + lane]) * (-1e9f);
    out[r * kA + lane] = a;
  }
}

extern "C" void kernel_launch(void* const* d_in, const int* in_sizes, int n_in,
                              void* d_out, int out_size, void* d_ws, size_t ws_size,
                              hipStream_t stream)
{
  (void)in_sizes; (void)n_in; (void)out_size; (void)ws_size;
  const float* x     = (const float*)d_in[0];
  const float* mask  = (const float*)d_in[1];
  const float* W_emb = (const float*)d_in[2];
  const float* b_emb = (const float*)d_in[3];
  const float* w_ih0 = (const float*)d_in[4];
  const float* w_hh0 = (const float*)d_in[5];
  const float* b_ih0 = (const float*)d_in[6];
  const float* b_hh0 = (const float*)d_in[7];
  const float* w_ih1 = (const float*)d_in[8];
  const float* w_hh1 = (const float*)d_in[9];
  const float* b_ih1 = (const float*)d_in[10];
  const float* b_hh1 = (const float*)d_in[11];
  const float* ln_g  = (const float*)d_in[12];
  const float* ln_b  = (const float*)d_in[13];
  const float* w1    = (const float*)d_in[14];
  const float* b1    = (const float*)d_in[15];
  const float* w2    = (const float*)d_in[16];
  const float* b2    = (const float*)d_in[17];
  float* out = (float*)d_out;

  // ws layout: h0ex[2][512][256] bf16 | h1ex[2][512][256] bf16 | flags[32][512] int
  unsigned short* h0ex = (unsigned short*)d_ws;
  unsigned short* h1ex = h0ex + 2 * kBH;
  int* flags = (int*)(h1ex + 2 * kBH);
  const size_t flag_bytes = (size_t)kNB * FLS * sizeof(int);  // 64 KiB

  // flags must start 0; h1ex parity-0 must be zeros (h1(-1)=0, gathered at p=1).
  hipMemsetAsync(flags, 0, flag_bytes, stream);
  hipMemsetAsync(h1ex, 0, (size_t)kBH * sizeof(unsigned short), stream);

  lstm_scan_kernel<<<dim3(kNP * kNS), dim3(kT), 0, stream>>>(
      x, W_emb, b_emb, w_ih0, w_hh0, b_ih0, b_hh0, w_ih1, w_hh1, b_ih1, b_hh1,
      h0ex, h1ex, flags, out);

  head_kernel<<<dim3(kB), dim3(64), 0, stream>>>(
      out + OUT_H + kBH, mask, ln_g, ln_b, w1, b1, w2, b2, out);
}

// Round 2
// 1493.020 us; speedup vs baseline: 1.2242x; 1.2242x over previous
//
#include <hip/hip_runtime.h>
#include <cstdint>
#include <cstddef>

typedef __attribute__((ext_vector_type(8))) short short8;
typedef __attribute__((ext_vector_type(4))) float f32x4;

#define MFMA16(a, b, c) __builtin_amdgcn_mfma_f32_16x16x32_bf16((a), (b), (c), 0, 0, 0)

constexpr int kB = 512, kS = 256, kI = 12, kH = 256, kA = 9;
constexpr int kNS = 16;   // hidden slices per btile (16 h-units each)
constexpr int kNB = 32;   // btiles (16 rows each)
constexpr int kT  = 256;  // 4 waves per block; 2 blocks/CU co-resident
constexpr int LDH = 264;  // padded LDS stride (bf16) for K=256 operand tiles
constexpr int LDG2 = 66;  // padded LDS stride (fp32) for 16x64 gate tiles
constexpr int kBH = kB * kH;
constexpr int FLS = 512;  // flag array stride per btile (ints)

// d_out layout (floats): [logits 512*9][h0 512*256][h1 512*256][c0 512*256][c1 512*256]
constexpr int OUT_H = kB * kA;              // 4608
constexpr int OUT_C = OUT_H + 2 * kBH;      // 266752

__device__ __forceinline__ short f2bf(float f) {  // RTNE fp32 -> bf16 bits
  uint32_t u = __float_as_uint(f);
  u += 0x7fffu + ((u >> 16) & 1u);
  return (short)(u >> 16);
}
__device__ __forceinline__ float fast_sigmoid(float v) {
  return __builtin_amdgcn_rcpf(1.f + __expf(-v));
}
__device__ __forceinline__ float fast_tanh(float v) {
  return 2.f * __builtin_amdgcn_rcpf(1.f + __expf(-2.f * v)) - 1.f;
}

// R6: occupancy-overlap. R5 proved the exchange is NOT the stall (explicit
// X/Y pairing hid nothing: superphase == 2x phase). The stall is serial,
// latency-exposed execution inside each block (barrier-separated short
// sections, redundant LDS A-fragment broadcast, trans-rate elementwise).
// Fix: TWO independent blocks per CU so the wave scheduler fills one
// block's stalls with the other block's ready waves.
//   - slice = 16 h-units -> 32 btiles x 16 slices = 512 blocks = 2/CU.
//   - block = 256 threads (4 waves); wave = (K-half kh, col-group cg):
//     owns 32 gate cols over K=128. A-fragment LDS reads per CU per phase
//     drop 192 -> 96 b128 (all-wave redundant broadcast halved).
//   - gates accumulate as 2 K-partials (gP[kh]); elem sums them.
// Residency guaranteed: LDS 42KB x2 < 160KB, __launch_bounds__(256,2)
// caps VGPR <= 256 -> 8 waves/CU -> spin protocol cannot deadlock.

__global__ __launch_bounds__(kT, 2) void lstm_scan_kernel(
    const float* __restrict__ x,
    const float* __restrict__ W_emb, const float* __restrict__ b_emb,
    const float* __restrict__ w_ih0, const float* __restrict__ w_hh0,
    const float* __restrict__ b_ih0, const float* __restrict__ b_hh0,
    const float* __restrict__ w_ih1, const float* __restrict__ w_hh1,
    const float* __restrict__ b_ih1, const float* __restrict__ b_hh1,
    unsigned short* __restrict__ h0ex, unsigned short* __restrict__ h1ex,
    int* __restrict__ flags,
    float* __restrict__ dout)
{
  const int tid   = threadIdx.x;
  const int btile = blockIdx.x & (kNB - 1);  // bid%8 == btile%8 -> all 16 slices share an XCD
  const int slice = blockIdx.x >> 5;         // 0..15
  const int b0    = btile * 16;
  const int lane  = tid & 63;
  const int wave  = tid >> 6;                // 0..3
  const int n16   = lane & 15;
  const int quad  = lane >> 4;
  const int kh    = wave >> 1;               // K-half: 0 -> k[0,128), 1 -> k[128,256)
  const int cg    = wave & 1;                // col-group: 32 gate cols

  __shared__ short embL[16 * LDH];   // emb(p) (bf16) A-operand
  __shared__ short hA[16 * LDH];     // h0(p-1) — layer0 recurrent AND layer1 input
  __shared__ short hB[16 * LDH];     // h1(p-2) — layer1 recurrent
  __shared__ float gP[2][2][16 * LDG2];  // [kh][layer] partial gates 16 x 64 fp32

  for (int i = tid; i < 16 * LDH; i += kT) { hA[i] = 0; hB[i] = 0; }

  // Weight B-fragments: wave owns gate cols (cg*2+f)*256 + slice*16 + n16,
  // f in {0,1}, for its K-half. B-frag: lane(n16,quad) holds B[k=quad*8+j][n].
  const float* Wm[4] = { w_ih0, w_hh0, w_ih1, w_hh1 };
  short8 wB[4][2][4];
  {
#pragma unroll
    for (int mat = 0; mat < 4; ++mat) {
#pragma unroll
      for (int f = 0; f < 2; ++f) {
        const int gcol = (cg * 2 + f) * kH + slice * 16 + n16;
        const float* wp = Wm[mat] + (size_t)gcol * kH + kh * 128;
#pragma unroll
        for (int kkk = 0; kkk < 4; ++kkk) {
          const float* p = wp + kkk * 32 + quad * 8;
          const float4 f0 = *(const float4*)p;
          const float4 f1 = *(const float4*)(p + 4);
          short8 v;
          v[0] = f2bf(f0.x); v[1] = f2bf(f0.y); v[2] = f2bf(f0.z); v[3] = f2bf(f0.w);
          v[4] = f2bf(f1.x); v[5] = f2bf(f1.y); v[6] = f2bf(f1.z); v[7] = f2bf(f1.w);
          wB[mat][f][kkk] = v;
        }
      }
    }
  }
  // Embedding weights (K=12 zero-padded to 32). Wave computes emb cols [wave*64, +64).
  short8 wE[4];
  float bembv[4];
#pragma unroll
  for (int i = 0; i < 4; ++i) {
    const int col = wave * 64 + i * 16 + n16;
    short8 v;
#pragma unroll
    for (int j = 0; j < 8; ++j) {
      const int k = quad * 8 + j;
      v[j] = (k < kI) ? f2bf(W_emb[col * kI + k]) : (short)0;
    }
    wE[i] = v;
    bembv[i] = b_emb[col];
  }
  // Elementwise mapping: thread = (row=tid>>4, col=tid&15); 1 hidden unit/layer.
  const int erow = tid >> 4;
  const int ec   = tid & 15;
  const int ecol = slice * 16 + ec;
  float bi0[4], bi1[4];
#pragma unroll
  for (int g = 0; g < 4; ++g) {
    bi0[g] = b_ih0[g * kH + ecol] + b_hh0[g * kH + ecol];
    bi1[g] = b_ih1[g * kH + ecol] + b_hh1[g * kH + ecol];
  }
  float c0v = 0.f, c1v = 0.f;

#define EMB_TILE(T)                                                         \
  {                                                                         \
    const float* xr = x + ((size_t)(b0 + n16) * kS + (T)) * kI;             \
    short8 xa;                                                              \
    _Pragma("unroll")                                                       \
    for (int j = 0; j < 8; ++j) {                                           \
      const int k = quad * 8 + j;                                           \
      xa[j] = (k < kI) ? f2bf(xr[k]) : (short)0;                            \
    }                                                                       \
    _Pragma("unroll")                                                       \
    for (int i = 0; i < 4; ++i) {                                           \
      f32x4 z = {0.f, 0.f, 0.f, 0.f};                                       \
      f32x4 e = MFMA16(xa, wE[i], z);                                       \
      const int col = wave * 64 + i * 16 + n16;                             \
      _Pragma("unroll")                                                     \
      for (int r = 0; r < 4; ++r) {                                         \
        float v = e[r] + bembv[i];                                          \
        v = v > 0.f ? v : 0.f;                                              \
        embL[(quad * 4 + r) * LDH + col] = f2bf(v);                         \
      }                                                                     \
    }                                                                       \
  }

  // -------- prologue: emb(0) --------
  EMB_TILE(0);
  __syncthreads();

  int* const fl = flags + btile * FLS;

  for (int p = 0; p <= kS; ++p) {
    const int par  = p & 1;
    const int parg = par ^ 1;  // (p-1)&1

    // ---- spin + gather h0(p-1)->hA, h1(p-2)->hB ----
    if (p >= 1) {
      while (__hip_atomic_load(fl + (p - 1), __ATOMIC_RELAXED,
                               __HIP_MEMORY_SCOPE_AGENT) < kNS)
        __builtin_amdgcn_s_sleep(1);
      const int rr = tid >> 4;
      const int cc = (tid & 15) * 16;
      const size_t base = (size_t)parg * kBH + (size_t)(b0 + rr) * kH + cc;
      const uint64_t* s0 = (const uint64_t*)&h0ex[base];
      const uint64_t* s1 = (const uint64_t*)&h1ex[base];
      uint64_t a0 = __hip_atomic_load(s0 + 0, __ATOMIC_RELAXED, __HIP_MEMORY_SCOPE_AGENT);
      uint64_t a1 = __hip_atomic_load(s0 + 1, __ATOMIC_RELAXED, __HIP_MEMORY_SCOPE_AGENT);
      uint64_t a2 = __hip_atomic_load(s0 + 2, __ATOMIC_RELAXED, __HIP_MEMORY_SCOPE_AGENT);
      uint64_t a3 = __hip_atomic_load(s0 + 3, __ATOMIC_RELAXED, __HIP_MEMORY_SCOPE_AGENT);
      uint64_t b0_ = __hip_atomic_load(s1 + 0, __ATOMIC_RELAXED, __HIP_MEMORY_SCOPE_AGENT);
      uint64_t b1_ = __hip_atomic_load(s1 + 1, __ATOMIC_RELAXED, __HIP_MEMORY_SCOPE_AGENT);
      uint64_t b2_ = __hip_atomic_load(s1 + 2, __ATOMIC_RELAXED, __HIP_MEMORY_SCOPE_AGENT);
      uint64_t b3_ = __hip_atomic_load(s1 + 3, __ATOMIC_RELAXED, __HIP_MEMORY_SCOPE_AGENT);
      uint64_t* dA = (uint64_t*)&hA[rr * LDH + cc];
      uint64_t* dB = (uint64_t*)&hB[rr * LDH + cc];
      dA[0] = a0; dA[1] = a1; dA[2] = a2; dA[3] = a3;
      dB[0] = b0_; dB[1] = b1_; dB[2] = b2_; dB[3] = b3_;
    }
    __syncthreads();  // B0: hA/hB (and embL from prev phase) visible

    // ---- head: both layers' partial gates for this wave's (kh, cg).
    //      12 ds_read_b128 + 32 MFMA per wave; hA frags feed 4 MFMAs each. ----
    {
      f32x4 a0[2] = {{0.f,0.f,0.f,0.f},{0.f,0.f,0.f,0.f}};
      f32x4 g1[2] = {{0.f,0.f,0.f,0.f},{0.f,0.f,0.f,0.f}};
#pragma unroll
      for (int kkk = 0; kkk < 4; ++kkk) {
        const short8 ha = *(const short8*)&hA[n16 * LDH + (kh * 4 + kkk) * 32 + quad * 8];
        a0[0] = MFMA16(ha, wB[1][0][kkk], a0[0]);
        a0[1] = MFMA16(ha, wB[1][1][kkk], a0[1]);
        g1[0] = MFMA16(ha, wB[2][0][kkk], g1[0]);
        g1[1] = MFMA16(ha, wB[2][1][kkk], g1[1]);
      }
#pragma unroll
      for (int kkk = 0; kkk < 4; ++kkk) {
        const short8 e = *(const short8*)&embL[n16 * LDH + (kh * 4 + kkk) * 32 + quad * 8];
        a0[0] = MFMA16(e, wB[0][0][kkk], a0[0]);
        a0[1] = MFMA16(e, wB[0][1][kkk], a0[1]);
      }
#pragma unroll
      for (int kkk = 0; kkk < 4; ++kkk) {
        const short8 hb = *(const short8*)&hB[n16 * LDH + (kh * 4 + kkk) * 32 + quad * 8];
        g1[0] = MFMA16(hb, wB[3][0][kkk], g1[0]);
        g1[1] = MFMA16(hb, wB[3][1][kkk], g1[1]);
      }
#pragma unroll
      for (int f = 0; f < 2; ++f) {
        const int lcol = cg * 32 + f * 16 + n16;
#pragma unroll
        for (int r = 0; r < 4; ++r) {
          gP[kh][0][(quad * 4 + r) * LDG2 + lcol] = a0[f][r];
          gP[kh][1][(quad * 4 + r) * LDG2 + lcol] = g1[f][r];
        }
      }
    }
    __syncthreads();  // B1: partial gate tiles ready

    // ---- elementwise layer0 (step p), guarded ----
    if (p < kS) {
      const float iv = gP[0][0][erow * LDG2 +      ec] + gP[1][0][erow * LDG2 +      ec] + bi0[0];
      const float fv = gP[0][0][erow * LDG2 + 16 + ec] + gP[1][0][erow * LDG2 + 16 + ec] + bi0[1];
      const float gv = gP[0][0][erow * LDG2 + 32 + ec] + gP[1][0][erow * LDG2 + 32 + ec] + bi0[2];
      const float ov = gP[0][0][erow * LDG2 + 48 + ec] + gP[1][0][erow * LDG2 + 48 + ec] + bi0[3];
      const float c = fast_sigmoid(fv) * c0v + fast_sigmoid(iv) * fast_tanh(gv);
      c0v = c;
      const float h = fast_sigmoid(ov) * fast_tanh(c);
      unsigned short* dst = &h0ex[(size_t)par * kBH + (size_t)(b0 + erow) * kH + ecol];
      __hip_atomic_store(dst, (unsigned short)f2bf(h), __ATOMIC_RELAXED, __HIP_MEMORY_SCOPE_AGENT);
      if (p == kS - 1) {
        dout[OUT_H + (size_t)(b0 + erow) * kH + ecol] = h;
        dout[OUT_C + (size_t)(b0 + erow) * kH + ecol] = c;
      }
    }
    // ---- elementwise layer1 (step p-1), guarded ----
    if (p >= 1) {
      const float iv = gP[0][1][erow * LDG2 +      ec] + gP[1][1][erow * LDG2 +      ec] + bi1[0];
      const float fv = gP[0][1][erow * LDG2 + 16 + ec] + gP[1][1][erow * LDG2 + 16 + ec] + bi1[1];
      const float gv = gP[0][1][erow * LDG2 + 32 + ec] + gP[1][1][erow * LDG2 + 32 + ec] + bi1[2];
      const float ov = gP[0][1][erow * LDG2 + 48 + ec] + gP[1][1][erow * LDG2 + 48 + ec] + bi1[3];
      const float c = fast_sigmoid(fv) * c1v + fast_sigmoid(iv) * fast_tanh(gv);
      c1v = c;
      const float h = fast_sigmoid(ov) * fast_tanh(c);
      unsigned short* dst = &h1ex[(size_t)par * kBH + (size_t)(b0 + erow) * kH + ecol];
      __hip_atomic_store(dst, (unsigned short)f2bf(h), __ATOMIC_RELAXED, __HIP_MEMORY_SCOPE_AGENT);
      if (p == kS) {
        dout[OUT_H + kBH + (size_t)(b0 + erow) * kH + ecol] = h;
        dout[OUT_C + kBH + (size_t)(b0 + erow) * kH + ecol] = c;
      }
    }
    __syncthreads();  // B2: drains vmcnt(0) -> exchange stores IC-visible

    if (p < kS) {
      // ---- publish (single flag covers h0(p) AND h1(p-1)) ----
      if (tid == 0)
        __hip_atomic_fetch_add(fl + p, 1, __ATOMIC_RELAXED, __HIP_MEMORY_SCOPE_AGENT);

      // ---- emb(p+1): overlaps flag/data propagation through the IC ----
      if (p + 1 < kS) EMB_TILE(p + 1);
      // next phase's B0 barrier covers embL visibility
    }
  }
#undef EMB_TILE
}

// LayerNorm + MLP head, exact fp32. One wave per batch row.
__global__ __launch_bounds__(64) void head_kernel(
    const float* __restrict__ h1last, const float* __restrict__ mask,
    const float* __restrict__ ln_g, const float* __restrict__ ln_b,
    const float* __restrict__ w1, const float* __restrict__ b1,
    const float* __restrict__ w2, const float* __restrict__ b2,
    float* __restrict__ out)
{
  const int r = blockIdx.x;
  const int lane = threadIdx.x;
  __shared__ float ns[kH];
  __shared__ float hd[32];
  const float4 v = *(const float4*)&h1last[r * kH + lane * 4];
  float vv[4] = {v.x, v.y, v.z, v.w};
  float s = vv[0] + vv[1] + vv[2] + vv[3];
#pragma unroll
  for (int off = 32; off > 0; off >>= 1) s += __shfl_xor(s, off, 64);
  const float mean = s * (1.f / kH);
  float q = 0.f;
#pragma unroll
  for (int j = 0; j < 4; ++j) { const float d = vv[j] - mean; q += d * d; }
#pragma unroll
  for (int off = 32; off > 0; off >>= 1) q += __shfl_xor(q, off, 64);
  const float rstd = rsqrtf(q * (1.f / kH) + 1e-5f);
#pragma unroll
  for (int j = 0; j < 4; ++j) {
    const int c = lane * 4 + j;
    ns[c] = (vv[j] - mean) * rstd * ln_g[c] + ln_b[c];
  }
  __syncthreads();
  if (lane < 32) {
    float a = b1[lane];
    const float* wr = w1 + lane * kH;
    for (int k = 0; k < kH; ++k) a += ns[k] * wr[k];
    hd[lane] = a > 0.f ? a : 0.f;
  }
  __syncthreads();
  if (lane < kA) {
    float a = b2[lane];
    const float* wr = w2 + lane * 32;
#pragma unroll
    for (int k = 0; k < 32; ++k) a += hd[k] * wr[k];
    a += (1.f - mask[r * kA + lane]) * (-1e9f);
    out[r * kA + lane] = a;
  }
}

extern "C" void kernel_launch(void* const* d_in, const int* in_sizes, int n_in,
                              void* d_out, int out_size, void* d_ws, size_t ws_size,
                              hipStream_t stream)
{
  (void)in_sizes; (void)n_in; (void)out_size; (void)ws_size;
  const float* x     = (const float*)d_in[0];
  const float* mask  = (const float*)d_in[1];
  const float* W_emb = (const float*)d_in[2];
  const float* b_emb = (const float*)d_in[3];
  const float* w_ih0 = (const float*)d_in[4];
  const float* w_hh0 = (const float*)d_in[5];
  const float* b_ih0 = (const float*)d_in[6];
  const float* b_hh0 = (const float*)d_in[7];
  const float* w_ih1 = (const float*)d_in[8];
  const float* w_hh1 = (const float*)d_in[9];
  const float* b_ih1 = (const float*)d_in[10];
  const float* b_hh1 = (const float*)d_in[11];
  const float* ln_g  = (const float*)d_in[12];
  const float* ln_b  = (const float*)d_in[13];
  const float* w1    = (const float*)d_in[14];
  const float* b1    = (const float*)d_in[15];
  const float* w2    = (const float*)d_in[16];
  const float* b2    = (const float*)d_in[17];
  float* out = (float*)d_out;

  // ws layout: h0ex[2][512][256] bf16 | h1ex[2][512][256] bf16 | flags[32][512] int
  unsigned short* h0ex = (unsigned short*)d_ws;
  unsigned short* h1ex = h0ex + 2 * kBH;
  int* flags = (int*)(h1ex + 2 * kBH);
  const size_t flag_bytes = (size_t)kNB * FLS * sizeof(int);  // 64 KiB

  // flags must start 0; h1ex parity-0 must be zeros (h1(-1)=0, gathered at p=1).
  hipMemsetAsync(flags, 0, flag_bytes, stream);
  hipMemsetAsync(h1ex, 0, (size_t)kBH * sizeof(unsigned short), stream);

  lstm_scan_kernel<<<dim3(kNB * kNS), dim3(kT), 0, stream>>>(
      x, W_emb, b_emb, w_ih0, w_hh0, b_ih0, b_hh0, w_ih1, w_hh1, b_ih1, b_hh1,
      h0ex, h1ex, flags, out);

  head_kernel<<<dim3(kB), dim3(64), 0, stream>>>(
      out + OUT_H + kBH, mask, ln_g, ln_b, w1, b1, w2, b2, out);
}

// Round 3
// 966.140 us; speedup vs baseline: 1.8917x; 1.5453x over previous
//
#include <hip/hip_runtime.h>
#include <cstdint>
#include <cstddef>

typedef __attribute__((ext_vector_type(8))) short short8;
typedef __attribute__((ext_vector_type(4))) float f32x4;

#define MFMA16(a, b, c) __builtin_amdgcn_mfma_f32_16x16x32_bf16((a), (b), (c), 0, 0, 0)

constexpr int kB = 512, kS = 256, kI = 12, kH = 256, kA = 9;
constexpr int kNS = 8;    // hidden slices per batch tile (32 h-units each)
constexpr int kNB = 32;   // batch tiles (16 rows each)
constexpr int kT  = 512;  // block size: 8 waves -> 2 waves/SIMD
constexpr int LDH = 264;  // padded LDS stride (bf16) for K=256 operand tiles
constexpr int LDG = 132;  // padded LDS stride (fp32) for 16x128 gate tiles
constexpr int kBH = kB * kH;
constexpr int FLS = 512;  // flag array stride per btile (ints)

// d_out layout (floats): [logits 512*9][h0 512*256][h1 512*256][c0 512*256][c1 512*256]
constexpr int OUT_H = kB * kA;              // 4608
constexpr int OUT_C = OUT_H + 2 * kBH;      // 266752

__device__ __forceinline__ short f2bf(float f) {  // RTNE fp32 -> bf16 bits
  uint32_t u = __float_as_uint(f);
  u += 0x7fffu + ((u >> 16) & 1u);
  return (short)(u >> 16);
}
__device__ __forceinline__ float fast_sigmoid(float v) {
  return __builtin_amdgcn_rcpf(1.f + __expf(-v));
}
__device__ __forceinline__ float fast_tanh(float v) {
  return 2.f * __builtin_amdgcn_rcpf(1.f + __expf(-2.f * v)) - 1.f;
}

// R7: SPILL FIX. R4/R6 reported VGPR_Count=128, but the weight cache alone
// (wB = 32 x short8) is 128 VGPRs; mandatory live state is ~150-190. The
// old __launch_bounds__(kT,2) capped the allocator at 128 -> ~50-60 VGPRs
// of weight fragments spilled to scratch and reloaded through L2 INSIDE
// the MFMA head loop every phase. R5's pairing experiment proved the
// per-phase stall travels with the block's own compute section (superphase
// == exactly 2x phase), consistent with spill-reload latency, not exchange
// latency. Fix: __launch_bounds__(512) only. Per-SIMD VGPR file = 2048,
// so the 8-wave block stays resident at 2 waves/SIMD for any VGPR count
// up to 512 -> grid 256 = 1 block/CU residency (spin protocol safe).
__global__ __launch_bounds__(kT) void lstm_scan_kernel(
    const float* __restrict__ x,
    const float* __restrict__ W_emb, const float* __restrict__ b_emb,
    const float* __restrict__ w_ih0, const float* __restrict__ w_hh0,
    const float* __restrict__ b_ih0, const float* __restrict__ b_hh0,
    const float* __restrict__ w_ih1, const float* __restrict__ w_hh1,
    const float* __restrict__ b_ih1, const float* __restrict__ b_hh1,
    unsigned short* __restrict__ h0ex, unsigned short* __restrict__ h1ex,
    int* __restrict__ flags,
    float* __restrict__ dout)
{
  const int tid   = threadIdx.x;
  const int btile = blockIdx.x & (kNB - 1);  // bid%32 -> slices of a btile share an XCD
  const int slice = blockIdx.x >> 5;
  const int b0    = btile * 16;
  const int lane  = tid & 63;
  const int wave  = tid >> 6;                // 0..7 == this wave's N-tile (16 gate cols)
  const int n16   = lane & 15;
  const int quad  = lane >> 4;

  __shared__ short embL[16 * LDH];   // emb(p) (bf16) A-operand
  __shared__ short hA[16 * LDH];     // h0(p-1) — feeds layer0 recurrence AND layer1 input
  __shared__ short hB[16 * LDH];     // h1(p-2) — feeds layer1 recurrence
  __shared__ float gL0[16 * LDG];    // layer0 gates 16 x 128 fp32
  __shared__ float gL1[16 * LDG];    // layer1 gates 16 x 128 fp32

  for (int i = tid; i < 16 * LDH; i += kT) { hA[i] = 0; hB[i] = 0; }

  // Weight B-fragments: this wave owns gate cols [lcol16, +16) where the
  // global gate col = (wave>>1)*256 + slice*32 + (wave&1)*16 + n16.
  // B-frag: lane(n=n16, quad) holds B[k=quad*8+j][n] (weights [4H,H] row-major).
  const float* Wm[4] = { w_ih0, w_hh0, w_ih1, w_hh1 };
  short8 wB[4][8];
  {
    const int gcol = (wave >> 1) * kH + slice * 32 + (wave & 1) * 16 + n16;
#pragma unroll
    for (int mat = 0; mat < 4; ++mat) {
      const float* wp = Wm[mat] + (size_t)gcol * kH;
#pragma unroll
      for (int kk = 0; kk < 8; ++kk) {
        const float* p = wp + kk * 32 + quad * 8;
        const float4 f0 = *(const float4*)p;
        const float4 f1 = *(const float4*)(p + 4);
        short8 v;
        v[0] = f2bf(f0.x); v[1] = f2bf(f0.y); v[2] = f2bf(f0.z); v[3] = f2bf(f0.w);
        v[4] = f2bf(f1.x); v[5] = f2bf(f1.y); v[6] = f2bf(f1.z); v[7] = f2bf(f1.w);
        wB[mat][kk] = v;
      }
    }
  }
  // Embedding weights (K=12 zero-padded to 32). Wave computes emb cols [wave*32, +32).
  short8 wE[2];
  float bembv[2];
#pragma unroll
  for (int i = 0; i < 2; ++i) {
    const int col = wave * 32 + i * 16 + n16;
    short8 v;
#pragma unroll
    for (int j = 0; j < 8; ++j) {
      const int k = quad * 8 + j;
      v[j] = (k < kI) ? f2bf(W_emb[col * kI + k]) : (short)0;
    }
    wE[i] = v;
    bembv[i] = b_emb[col];
  }
  // Elementwise mapping: thread = (row=tid>>5, col=tid&31); 1 hidden unit per layer.
  const int erow = tid >> 5;
  const int ec   = tid & 31;
  const int ecol = slice * 32 + ec;
  float bi0[4], bi1[4];
#pragma unroll
  for (int g = 0; g < 4; ++g) {
    bi0[g] = b_ih0[g * kH + ecol] + b_hh0[g * kH + ecol];
    bi1[g] = b_ih1[g * kH + ecol] + b_hh1[g * kH + ecol];
  }
  float c0v = 0.f, c1v = 0.f;

  // -------- prologue: emb(0) from direct global x loads --------
  {
    const float* xr = x + (size_t)(b0 + n16) * kS * kI;  // t = 0
    short8 xa;
#pragma unroll
    for (int j = 0; j < 8; ++j) {
      const int k = quad * 8 + j;
      xa[j] = (k < kI) ? f2bf(xr[k]) : (short)0;
    }
#pragma unroll
    for (int i = 0; i < 2; ++i) {
      f32x4 z = {0.f, 0.f, 0.f, 0.f};
      f32x4 e = MFMA16(xa, wE[i], z);
      const int col = wave * 32 + i * 16 + n16;
#pragma unroll
      for (int r = 0; r < 4; ++r) {
        float v = e[r] + bembv[i];
        v = v > 0.f ? v : 0.f;
        embL[(quad * 4 + r) * LDH + col] = f2bf(v);  // C-layout: row=quad*4+r
      }
    }
  }
  __syncthreads();

  int* const fl = flags + btile * FLS;

  for (int p = 0; p <= kS; ++p) {
    const int par = p & 1;

    // ---- head: both layers' gates; 32 MFMAs/wave (hA fragments shared).
    //      Edge phases compute don't-care values; state updates are guarded. ----
    {
      f32x4 a0 = {0.f,0.f,0.f,0.f}, g1 = a0;
#pragma unroll
      for (int kk = 0; kk < 8; ++kk) {
        const short8 ha = *(const short8*)&hA[n16 * LDH + kk * 32 + quad * 8];
        a0 = MFMA16(ha, wB[1][kk], a0);   // layer0 recurrent
        g1 = MFMA16(ha, wB[2][kk], g1);   // layer1 input (y0 = h0(p-1))
      }
#pragma unroll
      for (int kk = 0; kk < 8; ++kk) {
        const short8 e = *(const short8*)&embL[n16 * LDH + kk * 32 + quad * 8];
        a0 = MFMA16(e, wB[0][kk], a0);    // layer0 input
      }
#pragma unroll
      for (int kk = 0; kk < 8; ++kk) {
        const short8 hb = *(const short8*)&hB[n16 * LDH + kk * 32 + quad * 8];
        g1 = MFMA16(hb, wB[3][kk], g1);   // layer1 recurrent
      }
      const int lcol = (wave >> 1) * 32 + (wave & 1) * 16 + n16;
#pragma unroll
      for (int r = 0; r < 4; ++r) {
        gL0[(quad * 4 + r) * LDG + lcol] = a0[r];
        gL1[(quad * 4 + r) * LDG + lcol] = g1[r];
      }
    }
    __syncthreads();  // B1: gate tiles ready

    // ---- elementwise layer0 (step p), guarded ----
    if (p < kS) {
      const float iv = gL0[erow * LDG +       ec] + bi0[0];
      const float fv = gL0[erow * LDG +  32 + ec] + bi0[1];
      const float gv = gL0[erow * LDG +  64 + ec] + bi0[2];
      const float ov = gL0[erow * LDG +  96 + ec] + bi0[3];
      const float c = fast_sigmoid(fv) * c0v + fast_sigmoid(iv) * fast_tanh(gv);
      c0v = c;
      const float h = fast_sigmoid(ov) * fast_tanh(c);
      unsigned short* dst = &h0ex[(size_t)par * kBH + (size_t)(b0 + erow) * kH + ecol];
      __hip_atomic_store(dst, (unsigned short)f2bf(h), __ATOMIC_RELAXED, __HIP_MEMORY_SCOPE_AGENT);
      if (p == kS - 1) {
        dout[OUT_H + (size_t)(b0 + erow) * kH + ecol] = h;
        dout[OUT_C + (size_t)(b0 + erow) * kH + ecol] = c;
      }
    }
    // ---- elementwise layer1 (step p-1), guarded ----
    if (p >= 1) {
      const float iv = gL1[erow * LDG +       ec] + bi1[0];
      const float fv = gL1[erow * LDG +  32 + ec] + bi1[1];
      const float gv = gL1[erow * LDG +  64 + ec] + bi1[2];
      const float ov = gL1[erow * LDG +  96 + ec] + bi1[3];
      const float c = fast_sigmoid(fv) * c1v + fast_sigmoid(iv) * fast_tanh(gv);
      c1v = c;
      const float h = fast_sigmoid(ov) * fast_tanh(c);
      unsigned short* dst = &h1ex[(size_t)par * kBH + (size_t)(b0 + erow) * kH + ecol];
      __hip_atomic_store(dst, (unsigned short)f2bf(h), __ATOMIC_RELAXED, __HIP_MEMORY_SCOPE_AGENT);
      if (p == kS) {
        dout[OUT_H + kBH + (size_t)(b0 + erow) * kH + ecol] = h;
        dout[OUT_C + kBH + (size_t)(b0 + erow) * kH + ecol] = c;
      }
    }
    __syncthreads();  // B2: drains vmcnt(0) -> exchange stores IC-visible

    if (p < kS) {
      // ---- publish (single flag covers h0(p) AND h1(p-1)) ----
      if (tid == 0)
        __hip_atomic_fetch_add(fl + p, 1, __ATOMIC_RELAXED, __HIP_MEMORY_SCOPE_AGENT);

      // ---- emb(p+1): overlaps flag/data propagation through the IC ----
      if (p + 1 < kS) {
        const float* xr = x + ((size_t)(b0 + n16) * kS + (p + 1)) * kI;
        short8 xa;
#pragma unroll
        for (int j = 0; j < 8; ++j) {
          const int k = quad * 8 + j;
          xa[j] = (k < kI) ? f2bf(xr[k]) : (short)0;
        }
#pragma unroll
        for (int i = 0; i < 2; ++i) {
          f32x4 z = {0.f, 0.f, 0.f, 0.f};
          f32x4 e = MFMA16(xa, wE[i], z);
          const int col = wave * 32 + i * 16 + n16;
#pragma unroll
          for (int r = 0; r < 4; ++r) {
            float v = e[r] + bembv[i];
            v = v > 0.f ? v : 0.f;
            embL[(quad * 4 + r) * LDH + col] = f2bf(v);
          }
        }
      }

      // ---- all-thread spin (uniform exit) ----
      while (__hip_atomic_load(fl + p, __ATOMIC_RELAXED, __HIP_MEMORY_SCOPE_AGENT) < kNS)
        __builtin_amdgcn_s_sleep(1);

      // ---- gather h0(p) -> hA, h1(p-1) -> hB (relaxed u64 loads) ----
      {
        const int rr = tid >> 5;
        const int cc = (tid & 31) * 8;
        const size_t base = (size_t)par * kBH + (size_t)(b0 + rr) * kH + cc;
        const uint64_t* s0 = (const uint64_t*)&h0ex[base];
        const uint64_t* s1 = (const uint64_t*)&h1ex[base];
        uint64_t va0 = __hip_atomic_load(s0 + 0, __ATOMIC_RELAXED, __HIP_MEMORY_SCOPE_AGENT);
        uint64_t va1 = __hip_atomic_load(s0 + 1, __ATOMIC_RELAXED, __HIP_MEMORY_SCOPE_AGENT);
        uint64_t vb0 = __hip_atomic_load(s1 + 0, __ATOMIC_RELAXED, __HIP_MEMORY_SCOPE_AGENT);
        uint64_t vb1 = __hip_atomic_load(s1 + 1, __ATOMIC_RELAXED, __HIP_MEMORY_SCOPE_AGENT);
        uint64_t* dA = (uint64_t*)&hA[rr * LDH + cc];
        uint64_t* dB = (uint64_t*)&hB[rr * LDH + cc];
        dA[0] = va0; dA[1] = va1;
        dB[0] = vb0; dB[1] = vb1;
      }
      __syncthreads();  // B5: hA/hB/embL ready for next phase's head
    }
  }
}

// LayerNorm + MLP head, exact fp32. One wave per batch row.
__global__ __launch_bounds__(64) void head_kernel(
    const float* __restrict__ h1last, const float* __restrict__ mask,
    const float* __restrict__ ln_g, const float* __restrict__ ln_b,
    const float* __restrict__ w1, const float* __restrict__ b1,
    const float* __restrict__ w2, const float* __restrict__ b2,
    float* __restrict__ out)
{
  const int r = blockIdx.x;
  const int lane = threadIdx.x;
  __shared__ float ns[kH];
  __shared__ float hd[32];
  const float4 v = *(const float4*)&h1last[r * kH + lane * 4];
  float vv[4] = {v.x, v.y, v.z, v.w};
  float s = vv[0] + vv[1] + vv[2] + vv[3];
#pragma unroll
  for (int off = 32; off > 0; off >>= 1) s += __shfl_xor(s, off, 64);
  const float mean = s * (1.f / kH);
  float q = 0.f;
#pragma unroll
  for (int j = 0; j < 4; ++j) { const float d = vv[j] - mean; q += d * d; }
#pragma unroll
  for (int off = 32; off > 0; off >>= 1) q += __shfl_xor(q, off, 64);
  const float rstd = rsqrtf(q * (1.f / kH) + 1e-5f);
#pragma unroll
  for (int j = 0; j < 4; ++j) {
    const int c = lane * 4 + j;
    ns[c] = (vv[j] - mean) * rstd * ln_g[c] + ln_b[c];
  }
  __syncthreads();
  if (lane < 32) {
    float a = b1[lane];
    const float* wr = w1 + lane * kH;
    for (int k = 0; k < kH; ++k) a += ns[k] * wr[k];
    hd[lane] = a > 0.f ? a : 0.f;
  }
  __syncthreads();
  if (lane < kA) {
    float a = b2[lane];
    const float* wr = w2 + lane * 32;
#pragma unroll
    for (int k = 0; k < 32; ++k) a += hd[k] * wr[k];
    a += (1.f - mask[r * kA + lane]) * (-1e9f);
    out[r * kA + lane] = a;
  }
}

extern "C" void kernel_launch(void* const* d_in, const int* in_sizes, int n_in,
                              void* d_out, int out_size, void* d_ws, size_t ws_size,
                              hipStream_t stream)
{
  (void)in_sizes; (void)n_in; (void)out_size; (void)ws_size;
  const float* x     = (const float*)d_in[0];
  const float* mask  = (const float*)d_in[1];
  const float* W_emb = (const float*)d_in[2];
  const float* b_emb = (const float*)d_in[3];
  const float* w_ih0 = (const float*)d_in[4];
  const float* w_hh0 = (const float*)d_in[5];
  const float* b_ih0 = (const float*)d_in[6];
  const float* b_hh0 = (const float*)d_in[7];
  const float* w_ih1 = (const float*)d_in[8];
  const float* w_hh1 = (const float*)d_in[9];
  const float* b_ih1 = (const float*)d_in[10];
  const float* b_hh1 = (const float*)d_in[11];
  const float* ln_g  = (const float*)d_in[12];
  const float* ln_b  = (const float*)d_in[13];
  const float* w1    = (const float*)d_in[14];
  const float* b1    = (const float*)d_in[15];
  const float* w2    = (const float*)d_in[16];
  const float* b2    = (const float*)d_in[17];
  float* out = (float*)d_out;

  // ws layout: h0ex[2][512][256] bf16 | h1ex[2][512][256] bf16 | flags[32][512] int
  unsigned short* h0ex = (unsigned short*)d_ws;
  unsigned short* h1ex = h0ex + 2 * kBH;
  int* flags = (int*)(h1ex + 2 * kBH);
  const size_t flag_bytes = (size_t)kNB * FLS * sizeof(int);  // 64 KiB

  // flags must start 0; h1ex parity-0 must be zeros (h1(-1)=0, gathered at p=0).
  hipMemsetAsync(flags, 0, flag_bytes, stream);
  hipMemsetAsync(h1ex, 0, (size_t)kBH * sizeof(unsigned short), stream);

  lstm_scan_kernel<<<dim3(kNB * kNS), dim3(kT), 0, stream>>>(
      x, W_emb, b_emb, w_ih0, w_hh0, b_ih0, b_hh0, w_ih1, w_hh1, b_ih1, b_hh1,
      h0ex, h1ex, flags, out);

  head_kernel<<<dim3(kB), dim3(64), 0, stream>>>(
      out + OUT_H + kBH, mask, ln_g, ln_b, w1, b1, w2, b2, out);
}